// Round 3
// baseline (297.874 us; speedup 1.0000x reference)
//
#include <hip/hip_runtime.h>
#include <math.h>

#define TKK 512
#define TQQ 128
#define BB  8
#define EE  128
#define DD  82
#define IND 41
#define HH  128
#define G3  384
#define NL  50
#define OD  40

typedef __attribute__((ext_vector_type(8))) short short8v;
typedef __attribute__((ext_vector_type(4))) float f32x4;
#define MFMA16(a, b, c) __builtin_amdgcn_mfma_f32_16x16x32_bf16(a, b, c, 0, 0, 0)

__device__ __forceinline__ short f2bf(float f) {
  unsigned u = __float_as_uint(f);
  unsigned r = (u + 0x7fffu + ((u >> 16) & 1u)) >> 16;  // RNE
  return (short)r;
}

// ---------------- Kernel A: time embeddings + K/Q projections ----------------
__global__ void embed_project(const float* __restrict__ time_steps,
                              const float* __restrict__ query,
                              const float* __restrict__ e1_wp, const float* __restrict__ e1_bp,
                              const float* __restrict__ e1_wl, const float* __restrict__ e1_bl,
                              const float* __restrict__ e2_wp, const float* __restrict__ e2_bp,
                              const float* __restrict__ e2_wl, const float* __restrict__ e2_bl,
                              const float* __restrict__ Wk, const float* __restrict__ bk,
                              const float* __restrict__ Wq, const float* __restrict__ bq,
                              float* __restrict__ kproj, float* __restrict__ qproj) {
  __shared__ float emb[EE];
  int row = blockIdx.x;
  int e = threadIdx.x;
  float t; const float *wp, *bp, *wl, *bl, *W, *bias; float* out;
  if (row < BB * TKK) {
    t = time_steps[row];
    wp = e1_wp; bp = e1_bp; wl = e1_wl; bl = e1_bl; W = Wk; bias = bk;
    out = kproj + (size_t)row * EE;
  } else {
    int qi = row - BB * TKK;
    t = query[qi];
    wp = e2_wp; bp = e2_bp; wl = e2_wl; bl = e2_bl; W = Wq; bias = bq;
    out = qproj + (size_t)qi * EE;
  }
  emb[e] = (e == 0) ? (t * wl[0] + bl[0]) : sinf(t * wp[e - 1] + bp[e - 1]);
  __syncthreads();
  const float4* wr = (const float4*)(W + (size_t)e * EE);
  const float4* ev = (const float4*)emb;
  float acc = bias[e];
#pragma unroll 8
  for (int i = 0; i < EE / 4; i++) {
    float4 a = wr[i]; float4 c = ev[i];
    acc += a.x * c.x + a.y * c.y + a.z * c.z + a.w * c.w;
  }
  out[e] = acc;
}

// ---------------- Kernel B: masked-softmax attention + Wo projection ----------------
__global__ void attention(const float* __restrict__ x,
                          const float* __restrict__ kproj,
                          const float* __restrict__ qproj,
                          const float* __restrict__ Wo, const float* __restrict__ bo,
                          float* __restrict__ xs) {
  __shared__ float qv[EE];
  __shared__ float w[TKK];
  __shared__ float red[8];
  __shared__ float part[2 * DD];
  __shared__ float numb[DD];
  __shared__ float attb[DD];
  int b = blockIdx.x >> 7, q = blockIdx.x & 127;
  int tid = threadIdx.x;  // 256
  if (tid < EE) qv[tid] = qproj[(size_t)q * EE + tid];
  __syncthreads();
  float lmax = -1e30f;
  for (int r = 0; r < 2; r++) {
    int k = tid + r * 256;
    const float4* kr = (const float4*)(kproj + (size_t)(b * TKK + k) * EE);
    const float4* qv4 = (const float4*)qv;
    float acc = 0.f;
#pragma unroll 8
    for (int i = 0; i < EE / 4; i++) {
      float4 a = kr[i]; float4 c = qv4[i];
      acc += a.x * c.x + a.y * c.y + a.z * c.z + a.w * c.w;
    }
    acc *= 0.08838834764831845f;  // 1/sqrt(128)
    w[k] = acc;
    lmax = fmaxf(lmax, acc);
  }
  for (int off = 32; off; off >>= 1) lmax = fmaxf(lmax, __shfl_xor(lmax, off, 64));
  if ((tid & 63) == 0) red[tid >> 6] = lmax;
  __syncthreads();
  if (tid == 0) {
    float m = red[0];
    for (int i = 1; i < 4; i++) m = fmaxf(m, red[i]);
    red[0] = m;
  }
  __syncthreads();
  float m = red[0];
  for (int r = 0; r < 2; r++) { int k = tid + r * 256; w[k] = __expf(w[k] - m); }
  __syncthreads();
  if (tid < 2 * DD) {
    int c = tid / DD, d = tid - c * DD;
    const float* xp = x + (size_t)(b * TKK + c * 256) * DD + d;
    float acc = 0.f;
#pragma unroll 4
    for (int k = 0; k < 256; k++) acc += w[c * 256 + k] * xp[(size_t)k * DD];
    part[tid] = acc;
  }
  __syncthreads();
  if (tid < DD) numb[tid] = part[tid] + part[DD + tid];
  __syncthreads();
  if (tid < DD) {
    int j = tid % IND;
    attb[tid] = numb[tid] / numb[IND + j];
  }
  __syncthreads();
  if (tid < HH) {
    const float* wo = Wo + (size_t)tid * DD;
    float acc = bo[tid];
#pragma unroll 2
    for (int d = 0; d < DD; d++) acc += wo[d] * attb[d];
    xs[((size_t)q * BB + b) * HH + tid] = acc;  // xs layout [TQ][B][H]
  }
}

// ---------------- Kernel C: precompute input gates gi ----------------
__global__ void gi_precompute(const float* __restrict__ xs,
                              const float* __restrict__ gwi_f, const float* __restrict__ gbi_f,
                              const float* __restrict__ gwi_b, const float* __restrict__ gbi_b,
                              float* __restrict__ gi) {
  __shared__ float xr[BB][EE];
  int dir = blockIdx.x >> 7, t = blockIdx.x & 127;
  const float* Wi = dir ? gwi_b : gwi_f;
  const float* bi = dir ? gbi_b : gbi_f;
  int tid = threadIdx.x;  // 384
  for (int idx = tid; idx < BB * EE; idx += G3)
    xr[idx >> 7][idx & 127] = xs[(size_t)t * BB * EE + idx];
  __syncthreads();
  const float* wr = Wi + (size_t)tid * EE;
  float bias = bi[tid];
  float acc[BB];
#pragma unroll
  for (int b = 0; b < BB; b++) acc[b] = bias;
  for (int i = 0; i < EE; i++) {
    float wv = wr[i];
#pragma unroll
    for (int b = 0; b < BB; b++) acc[b] += wv * xr[b][i];
  }
  size_t base = ((size_t)(dir * TQQ + t) * BB) * G3 + tid;
#pragma unroll
  for (int b = 0; b < BB; b++) gi[base + (size_t)b * G3] = acc[b];
}

// ---------------- Kernel D: sequential GRU via MFMA ----------------
// 2 blocks (one per direction), 512 threads = 8 waves.
// Per step: D[b][gate-tile] = h(8x128,bf16) x WhT(128x384,bf16) via
// mfma_f32_16x16x32_bf16. Wave w owns gate tiles {w, w+8, w+16} so r/z/n for
// output o=16w+(lane&15), row b=4*(lane>>4)+j land in the same lane/reg.
// h double-buffered bf16 in LDS with XOR swizzle; one barrier/step.
__global__ __launch_bounds__(512, 1) void gru_seq(const float* __restrict__ gi,
                                                  const float* __restrict__ gwh_f,
                                                  const float* __restrict__ gbh_f,
                                                  const float* __restrict__ gwh_b,
                                                  const float* __restrict__ gbh_b,
                                                  float* __restrict__ hcat) {
  __shared__ short hb[2][16][HH];  // bf16, rows 8..15 stay zero (MFMA M=16 pad)
  int dir = blockIdx.x;
  const float* Wh = dir ? gwh_b : gwh_f;
  const float* bh = dir ? gbh_b : gbh_f;
  int tid = threadIdx.x;
  int w = tid >> 6, l = tid & 63;
  int lhi = l >> 4, llo = l & 15;
  int o = 16 * w + llo;            // gate/output column this thread covers
  bool valid = (lhi < 2);          // rows b = 4*lhi+j < 8

  // zero both h buffers
  for (int i = tid; i < 2 * 16 * HH / 2; i += 512) ((int*)hb)[i] = 0;

  // B fragments: B[k][n] = Wh[n][k], n = g*128 + o, lane holds k=kk*32+8*lhi+[0..8)
  short8v Bf[3][4];
#pragma unroll
  for (int g = 0; g < 3; g++) {
    const float* wr = Wh + (size_t)(g * HH + o) * EE;
#pragma unroll
    for (int kk = 0; kk < 4; kk++) {
      int k0 = kk * 32 + lhi * 8;
      short8v v;
#pragma unroll
      for (int i = 0; i < 8; i++) v[i] = f2bf(wr[k0 + i]);
      Bf[g][kk] = v;
    }
  }
  float bhr = bh[o], bhz = bh[HH + o], bhn = bh[2 * HH + o];
  float hprev[4] = {0.f, 0.f, 0.f, 0.f};
  int swzA = (llo & 7) << 4;
  __syncthreads();

  for (int step = 0; step < TQQ; step++) {
    int t = dir ? (TQQ - 1 - step) : step;
    int cur = step & 1;
    // A fragments: A[m][k] = h[m][k], m = llo, k = kk*32 + 8*lhi + [0..8)
    const char* hrow = (const char*)&hb[cur][llo][0];
    short8v A0 = *(const short8v*)(hrow + ((0 * 64 + lhi * 16) ^ swzA));
    short8v A1 = *(const short8v*)(hrow + ((1 * 64 + lhi * 16) ^ swzA));
    short8v A2 = *(const short8v*)(hrow + ((2 * 64 + lhi * 16) ^ swzA));
    short8v A3 = *(const short8v*)(hrow + ((3 * 64 + lhi * 16) ^ swzA));
    // prefetch gi (consumed after MFMAs)
    float gir[4], giz[4], gin[4];
    if (valid) {
      size_t baset = (size_t)(dir * TQQ + t) * (BB * G3);
#pragma unroll
      for (int j = 0; j < 4; j++) {
        const float* gp = gi + baset + (size_t)(4 * lhi + j) * G3 + o;
        gir[j] = gp[0]; giz[j] = gp[HH]; gin[j] = gp[2 * HH];
      }
    }
    f32x4 accR = {0.f, 0.f, 0.f, 0.f}, accZ = {0.f, 0.f, 0.f, 0.f}, accN = {0.f, 0.f, 0.f, 0.f};
    accR = MFMA16(A0, Bf[0][0], accR); accZ = MFMA16(A0, Bf[1][0], accZ); accN = MFMA16(A0, Bf[2][0], accN);
    accR = MFMA16(A1, Bf[0][1], accR); accZ = MFMA16(A1, Bf[1][1], accZ); accN = MFMA16(A1, Bf[2][1], accN);
    accR = MFMA16(A2, Bf[0][2], accR); accZ = MFMA16(A2, Bf[1][2], accZ); accN = MFMA16(A2, Bf[2][2], accN);
    accR = MFMA16(A3, Bf[0][3], accR); accZ = MFMA16(A3, Bf[1][3], accZ); accN = MFMA16(A3, Bf[2][3], accN);
    if (valid) {
#pragma unroll
      for (int j = 0; j < 4; j++) {
        int m = 4 * lhi + j;  // batch row
        float rp = gir[j] + bhr + accR[j];
        float zp = giz[j] + bhz + accZ[j];
        float hn = accN[j] + bhn;
        float r = 1.f / (1.f + __expf(-rp));
        float z = 1.f / (1.f + __expf(-zp));
        float a = gin[j] + r * hn;
        float e = __expf(2.f * a);
        float n = 1.f - 2.f / (1.f + e);  // tanh(a), saturation-safe
        float hnew = n + z * (hprev[j] - n);
        hprev[j] = hnew;
        *(short*)((char*)&hb[cur ^ 1][m][0] + ((o * 2) ^ ((m & 7) << 4))) = f2bf(hnew);
        hcat[((size_t)m * TQQ + t) * (2 * HH) + dir * HH + o] = hnew;
      }
    }
    __syncthreads();
  }
}

// ---------------- Kernel E: final MLP ----------------
__global__ void mlp_out(const float* __restrict__ hcat,
                        const float* __restrict__ W1, const float* __restrict__ b1,
                        const float* __restrict__ W2, const float* __restrict__ b2,
                        float* __restrict__ out) {
  __shared__ float hrow[2 * HH];
  __shared__ float ybuf[NL];
  int bt = blockIdx.x;
  int tid = threadIdx.x;  // 64
  for (int idx = tid; idx < 2 * HH; idx += 64) hrow[idx] = hcat[(size_t)bt * 2 * HH + idx];
  __syncthreads();
  if (tid < NL) {
    const float* wr = W1 + (size_t)tid * 2 * HH;
    float acc = b1[tid];
#pragma unroll 4
    for (int i = 0; i < 2 * HH; i++) acc += wr[i] * hrow[i];
    ybuf[tid] = fmaxf(acc, 0.f);
  }
  __syncthreads();
  if (tid < OD) {
    const float* wr = W2 + (size_t)tid * NL;
    float acc = b2[tid];
#pragma unroll 2
    for (int j = 0; j < NL; j++) acc += wr[j] * ybuf[j];
    out[(size_t)bt * OD + tid] = acc;
  }
}

extern "C" void kernel_launch(void* const* d_in, const int* in_sizes, int n_in,
                              void* d_out, int out_size, void* d_ws, size_t ws_size,
                              hipStream_t stream) {
  const float* x          = (const float*)d_in[0];
  const float* time_steps = (const float*)d_in[1];
  const float* query      = (const float*)d_in[2];
  const float* e1_wp = (const float*)d_in[3];
  const float* e1_bp = (const float*)d_in[4];
  const float* e1_wl = (const float*)d_in[5];
  const float* e1_bl = (const float*)d_in[6];
  const float* e2_wp = (const float*)d_in[7];
  const float* e2_bp = (const float*)d_in[8];
  const float* e2_wl = (const float*)d_in[9];
  const float* e2_bl = (const float*)d_in[10];
  const float* Wq = (const float*)d_in[11];
  const float* bq = (const float*)d_in[12];
  const float* Wk = (const float*)d_in[13];
  const float* bk = (const float*)d_in[14];
  const float* Wo = (const float*)d_in[15];
  const float* bo = (const float*)d_in[16];
  const float* gwi_f = (const float*)d_in[17];
  const float* gwh_f = (const float*)d_in[18];
  const float* gbi_f = (const float*)d_in[19];
  const float* gbh_f = (const float*)d_in[20];
  const float* gwi_b = (const float*)d_in[21];
  const float* gwh_b = (const float*)d_in[22];
  const float* gbi_b = (const float*)d_in[23];
  const float* gbh_b = (const float*)d_in[24];
  const float* W1 = (const float*)d_in[25];
  const float* b1 = (const float*)d_in[26];
  const float* W2 = (const float*)d_in[27];
  const float* b2 = (const float*)d_in[28];

  float* ws    = (float*)d_ws;
  float* kproj = ws;                       // 4096*128
  float* qproj = kproj + 4096 * 128;       // 128*128
  float* xs    = qproj + 128 * 128;        // 128*8*128
  float* gi    = xs + 128 * 8 * 128;       // 2*128*8*384
  float* hcat  = gi + 2 * 128 * 8 * 384;   // 8*128*256

  embed_project<<<4224, 128, 0, stream>>>(time_steps, query,
                                          e1_wp, e1_bp, e1_wl, e1_bl,
                                          e2_wp, e2_bp, e2_wl, e2_bl,
                                          Wk, bk, Wq, bq, kproj, qproj);
  attention<<<1024, 256, 0, stream>>>(x, kproj, qproj, Wo, bo, xs);
  gi_precompute<<<256, 384, 0, stream>>>(xs, gwi_f, gbi_f, gwi_b, gbi_b, gi);
  gru_seq<<<2, 512, 0, stream>>>(gi, gwh_f, gbh_f, gwh_b, gbh_b, hcat);
  mlp_out<<<1024, 64, 0, stream>>>(hcat, W1, b1, W2, b2, (float*)d_out);
}